// Round 3
// baseline (575.348 us; speedup 1.0000x reference)
//
#include <hip/hip_runtime.h>
#include <stdint.h>
#include <stddef.h>

#define T_SEQ 2048
#define NH    12
#define DH    64
#define NB    2
#define NEMB  768

using f32x4  = __attribute__((ext_vector_type(4))) float;
using bf16x8 = __attribute__((ext_vector_type(8))) short;
using bf16x4 = __attribute__((ext_vector_type(4))) short;

#define MFMA(a, b, c) __builtin_amdgcn_mfma_f32_16x16x32_bf16((a), (b), (c), 0, 0, 0)

extern "C" __device__ float __ocml_native_exp2_f32(float);

__device__ __forceinline__ short f2bf(float f) {
    union { float f; uint32_t u; } v; v.f = f;
    uint32_t u = v.u + 0x7FFFu + ((v.u >> 16) & 1u);
    return (short)(u >> 16);
}
__device__ __forceinline__ float b2f(short s) {
    union { uint32_t u; float f; } v; v.u = ((uint32_t)(uint16_t)s) << 16;
    return v.f;
}

// ---------------------------------------------------------------------------
// Kernel 1: fp32 -> bf16 conversion. w_q additionally scaled by 1/8*log2(e)
// so that softmax exp becomes a single exp2.
// ---------------------------------------------------------------------------
__global__ void cvt_kernel(const float* __restrict__ x,  const float* __restrict__ wq,
                           const float* __restrict__ wk, const float* __restrict__ wv,
                           const float* __restrict__ wo,
                           short* __restrict__ xb,  short* __restrict__ wqb,
                           short* __restrict__ wkb, short* __restrict__ wvb,
                           short* __restrict__ wob) {
    const float* src; short* dst; int n; float scale = 1.0f;
    switch (blockIdx.y) {
        case 0:  src = x;  dst = xb;  n = NB * T_SEQ * NEMB; break;
        case 1:  src = wq; dst = wqb; n = NEMB * NEMB; scale = 0.18033688737f; break; // 0.125*log2(e)
        case 2:  src = wk; dst = wkb; n = NEMB * NEMB; break;
        case 3:  src = wv; dst = wvb; n = NEMB * NEMB; break;
        default: src = wo; dst = wob; n = NEMB * NEMB; break;
    }
    int n4 = n >> 2;
    for (int i = blockIdx.x * blockDim.x + threadIdx.x; i < n4; i += gridDim.x * blockDim.x) {
        float4 v = ((const float4*)src)[i];
        short4 o;
        o.x = f2bf(v.x * scale); o.y = f2bf(v.y * scale);
        o.z = f2bf(v.z * scale); o.w = f2bf(v.w * scale);
        ((short4*)dst)[i] = o;
    }
}

// ---------------------------------------------------------------------------
// Kernel 2: QKV projection GEMM.  C[t,d] = sum_c xb[t,c] * W[d,c]
// ---------------------------------------------------------------------------
__global__ __launch_bounds__(256, 2) void qkv_gemm(
        const short* __restrict__ xb,  const short* __restrict__ wqb,
        const short* __restrict__ wkb, const short* __restrict__ wvb,
        short* __restrict__ Qh, short* __restrict__ Kh, short* __restrict__ Vt) {
    __shared__ short As[128 * 64];
    __shared__ short Bs[128 * 64];
    const int mode = blockIdx.z;
    const short* Wm = (mode == 0) ? wqb : (mode == 1) ? wkb : wvb;
    const int rowbase = blockIdx.x * 128;
    const int colbase = blockIdx.y * 128;
    const int tid = threadIdx.x;
    const int lane = tid & 63;
    const int wid = tid >> 6;
    const int wm = wid >> 1, wn = wid & 1;
    const int g = lane >> 4, c = lane & 15;

    const f32x4 z4 = {0.f, 0.f, 0.f, 0.f};
    f32x4 acc[4][4];
#pragma unroll
    for (int i = 0; i < 4; ++i)
#pragma unroll
        for (int j = 0; j < 4; ++j) acc[i][j] = z4;

    for (int kt = 0; kt < 12; ++kt) {
        __syncthreads();
#pragma unroll
        for (int p = 0; p < 4; ++p) {
            int lin = p * 256 + tid;
            int row = lin >> 3, kb = lin & 7;
            int sw = ((kb * 16) ^ ((row & 7) << 4)) >> 1;
            *(bf16x8*)&As[row * 64 + sw] = *(const bf16x8*)&xb[(rowbase + row) * NEMB + kt * 64 + kb * 8];
            *(bf16x8*)&Bs[row * 64 + sw] = *(const bf16x8*)&Wm[(colbase + row) * NEMB + kt * 64 + kb * 8];
        }
        __syncthreads();
#pragma unroll
        for (int ks = 0; ks < 2; ++ks) {
            bf16x8 a[4], b[4];
#pragma unroll
            for (int mi = 0; mi < 4; ++mi) {
                int row = wm * 64 + mi * 16 + c;
                int kb = ((ks * 64 + g * 16) ^ ((row & 7) << 4)) >> 1;
                a[mi] = *(const bf16x8*)&As[row * 64 + kb];
            }
#pragma unroll
            for (int ni = 0; ni < 4; ++ni) {
                int row = wn * 64 + ni * 16 + c;
                int kb = ((ks * 64 + g * 16) ^ ((row & 7) << 4)) >> 1;
                b[ni] = *(const bf16x8*)&Bs[row * 64 + kb];
            }
#pragma unroll
            for (int mi = 0; mi < 4; ++mi)
#pragma unroll
                for (int ni = 0; ni < 4; ++ni)
                    acc[mi][ni] = MFMA(a[mi], b[ni], acc[mi][ni]);
        }
    }
#pragma unroll
    for (int mi = 0; mi < 4; ++mi) {
        int trow0 = rowbase + wm * 64 + mi * 16 + g * 4;
#pragma unroll
        for (int ni = 0; ni < 4; ++ni) {
            int col = colbase + wn * 64 + ni * 16 + c;
            int h = col >> 6, dh = col & 63;
#pragma unroll
            for (int r = 0; r < 4; ++r) {
                int trow = trow0 + r;
                int bb = trow >> 11, t = trow & 2047;
                int bh = bb * NH + h;
                short val = f2bf(acc[mi][ni][r]);
                if (mode == 2)      Vt[(size_t)bh * (DH * T_SEQ) + dh * T_SEQ + t] = val;
                else if (mode == 0) Qh[((size_t)bh * T_SEQ + t) * DH + dh] = val;
                else                Kh[((size_t)bh * T_SEQ + t) * DH + dh] = val;
            }
        }
    }
}

// ---------------------------------------------------------------------------
// Kernel 3: fused causal attention, swapped-QK layout.
//   MFMA(K, Q): lane holds 4 consecutive k-cols of one q-row -> vector-friendly.
//   pass 1: exact denominators (single exp2; scale folded into w_q).
//   pass 2: recompute S, normalized P (bf16) -> LDS; PV from LDS;
//           W written from LDS as contiguous 256B/row nontemporal dwordx4.
// ---------------------------------------------------------------------------
__global__ __launch_bounds__(256, 2) void attn_kernel(
        const short* __restrict__ Qh, const short* __restrict__ Kh,
        const short* __restrict__ Vt, float* __restrict__ Wout,
        short* __restrict__ Ob) {
    __shared__ short Ks[64 * 64];
    __shared__ short Vs[64 * 64];
    __shared__ short Ps[4][32 * 64];

    const int bh = blockIdx.y;
    const int bb = bh / NH, h = bh % NH;
    const int qtile = blockIdx.x;
    const int qbase = qtile * 128;
    const int tid = threadIdx.x, lane = tid & 63, w = tid >> 6;
    const int g = lane >> 4, c = lane & 15;
    const int nkt = 2 * (qtile + 1);
    const int stripmax = qbase + w * 32 + 31;

    const short* Qp = Qh + (size_t)bh * T_SEQ * DH;
    const short* Kp = Kh + (size_t)bh * T_SEQ * DH;
    const short* Vp = Vt + (size_t)bh * DH * T_SEQ;
    float* Wp = Wout + (size_t)bh * T_SEQ * T_SEQ;

    const f32x4 z4 = {0.f, 0.f, 0.f, 0.f};

    // Q fragments (B-operand now): row = c, k = g*8+i
    bf16x8 q[2][2];
#pragma unroll
    for (int mi = 0; mi < 2; ++mi)
#pragma unroll
        for (int ks = 0; ks < 2; ++ks)
            q[mi][ks] = *(const bf16x8*)&Qp[(qbase + w * 32 + mi * 16 + c) * DH + ks * 32 + g * 8];

    // ---- pass 1: denominators ----
    float lsum[2] = {0.f, 0.f};
    for (int kt = 0; kt < nkt; ++kt) {
        __syncthreads();
#pragma unroll
        for (int p = 0; p < 2; ++p) {
            int lin = p * 256 + tid;
            int row = lin >> 3, kb = lin & 7;
            int sw = ((kb * 16) ^ ((row & 7) << 4)) >> 1;
            *(bf16x8*)&Ks[row * 64 + sw] = *(const bf16x8*)&Kp[(kt * 64 + row) * DH + kb * 8];
        }
        __syncthreads();
        if (kt * 64 > stripmax) continue;
#pragma unroll
        for (int ni = 0; ni < 4; ++ni) {
            f32x4 s[2] = {z4, z4};
#pragma unroll
            for (int ks = 0; ks < 2; ++ks) {
                int krow = ni * 16 + c;
                int kb = ((ks * 64 + g * 16) ^ ((krow & 7) << 4)) >> 1;
                bf16x8 kf = *(const bf16x8*)&Ks[krow * 64 + kb];
                s[0] = MFMA(kf, q[0][ks], s[0]);   // swapped: D col = q-row, D row = k-col
                s[1] = MFMA(kf, q[1][ks], s[1]);
            }
            int bcol = kt * 64 + ni * 16 + g * 4;
#pragma unroll
            for (int mi = 0; mi < 2; ++mi) {
                int rowg = qbase + w * 32 + mi * 16 + c;
#pragma unroll
                for (int r = 0; r < 4; ++r) {
                    float e = __ocml_native_exp2_f32(s[mi][r]);
                    lsum[mi] += (bcol + r <= rowg) ? e : 0.f;
                }
            }
        }
    }
    float rl[2];
#pragma unroll
    for (int mi = 0; mi < 2; ++mi) {
        float t = lsum[mi];
        t += __shfl_xor(t, 16);
        t += __shfl_xor(t, 32);
        rl[mi] = __builtin_amdgcn_rcpf(t);
    }

    // ---- pass 2: P -> LDS, W full-line writes, PV ----
    f32x4 o[2][4];
#pragma unroll
    for (int mi = 0; mi < 2; ++mi)
#pragma unroll
        for (int di = 0; di < 4; ++di) o[mi][di] = z4;

    const int wl8 = lane >> 3;          // 0..7: row-within-8 for the W writer
    const int cl8 = lane & 7;           // 0..7: 8-col group for the W writer

    for (int kt = 0; kt < nkt; ++kt) {
        __syncthreads();
#pragma unroll
        for (int p = 0; p < 2; ++p) {
            int lin = p * 256 + tid;
            int row = lin >> 3, kb = lin & 7;
            int sw = ((kb * 16) ^ ((row & 7) << 4)) >> 1;
            *(bf16x8*)&Ks[row * 64 + sw] = *(const bf16x8*)&Kp[(kt * 64 + row) * DH + kb * 8];
            *(bf16x8*)&Vs[row * 64 + sw] = *(const bf16x8*)&Vp[row * T_SEQ + kt * 64 + kb * 8];
        }
        __syncthreads();
        if (kt * 64 > stripmax) {
            // fully masked: contiguous 256B-per-row zero stores
#pragma unroll
            for (int it = 0; it < 4; ++it) {
                float* dst = Wp + (size_t)(qbase + w * 32 + it * 8 + wl8) * T_SEQ + kt * 64 + cl8 * 8;
                __builtin_nontemporal_store(z4, (f32x4*)dst);
                __builtin_nontemporal_store(z4, (f32x4*)(dst + 4));
            }
            continue;
        }
        // QK^T (swapped) + normalize + pack P into LDS
#pragma unroll
        for (int ni = 0; ni < 4; ++ni) {
            f32x4 s[2] = {z4, z4};
#pragma unroll
            for (int ks = 0; ks < 2; ++ks) {
                int krow = ni * 16 + c;
                int kb = ((ks * 64 + g * 16) ^ ((krow & 7) << 4)) >> 1;
                bf16x8 kf = *(const bf16x8*)&Ks[krow * 64 + kb];
                s[0] = MFMA(kf, q[0][ks], s[0]);
                s[1] = MFMA(kf, q[1][ks], s[1]);
            }
            int bcol = kt * 64 + ni * 16 + g * 4;
#pragma unroll
            for (int mi = 0; mi < 2; ++mi) {
                int rowg = qbase + w * 32 + mi * 16 + c;
                bf16x4 pk;
#pragma unroll
                for (int r = 0; r < 4; ++r) {
                    float e = __ocml_native_exp2_f32(s[mi][r]) * rl[mi];
                    float wgt = (bcol + r <= rowg) ? e : 0.f;
                    pk[r] = f2bf(wgt);
                }
                int prow = mi * 16 + c;
                int sw = ((ni * 32 + g * 8) ^ ((prow & 7) << 4)) >> 1;
                *(bf16x4*)&Ps[w][prow * 64 + sw] = pk;
            }
        }
        // PV: O += P @ V   (A = P from LDS, B = V^T from LDS)
#pragma unroll
        for (int ks = 0; ks < 2; ++ks) {
            bf16x8 pa[2];
#pragma unroll
            for (int mi = 0; mi < 2; ++mi) {
                int prow = mi * 16 + c;
                int kb = ((ks * 64 + g * 16) ^ ((prow & 7) << 4)) >> 1;
                pa[mi] = *(const bf16x8*)&Ps[w][prow * 64 + kb];
            }
#pragma unroll
            for (int di = 0; di < 4; ++di) {
                int vrow = di * 16 + c;
                int kb = ((ks * 64 + g * 16) ^ ((vrow & 7) << 4)) >> 1;
                bf16x8 vf = *(const bf16x8*)&Vs[vrow * 64 + kb];
                o[0][di] = MFMA(pa[0], vf, o[0][di]);
                o[1][di] = MFMA(pa[1], vf, o[1][di]);
            }
        }
        // W writer: re-read own P strip, store contiguous 256B per row (fp32)
#pragma unroll
        for (int it = 0; it < 4; ++it) {
            int prow = it * 8 + wl8;
            int sw = ((cl8 * 16) ^ ((prow & 7) << 4)) >> 1;
            bf16x8 pv8 = *(const bf16x8*)&Ps[w][prow * 64 + sw];
            float* dst = Wp + (size_t)(qbase + w * 32 + prow) * T_SEQ + kt * 64 + cl8 * 8;
            f32x4 lo = {b2f(pv8[0]), b2f(pv8[1]), b2f(pv8[2]), b2f(pv8[3])};
            f32x4 hi = {b2f(pv8[4]), b2f(pv8[5]), b2f(pv8[6]), b2f(pv8[7])};
            __builtin_nontemporal_store(lo, (f32x4*)dst);
            __builtin_nontemporal_store(hi, (f32x4*)(dst + 4));
        }
    }

    // zero-fill strictly-upper region beyond the block's tiles
    int c0 = nkt * 64;
    if (c0 < T_SEQ) {
        for (int r = 0; r < 128; ++r) {
            float* base = Wp + (size_t)(qbase + r) * T_SEQ;
            for (int cc = c0 + tid * 4; cc < T_SEQ; cc += 1024)
                __builtin_nontemporal_store(z4, (f32x4*)(base + cc));
        }
    }

    // write O (bf16) into [4096][768] for the output projection
#pragma unroll
    for (int mi = 0; mi < 2; ++mi)
#pragma unroll
        for (int di = 0; di < 4; ++di)
#pragma unroll
            for (int r = 0; r < 4; ++r) {
                int rowg = qbase + w * 32 + mi * 16 + g * 4 + r;
                Ob[(size_t)(bb * T_SEQ + rowg) * NEMB + h * 64 + di * 16 + c] = f2bf(o[mi][di][r]);
            }
}

// ---------------------------------------------------------------------------
// Kernel 4: output projection.  final[t,d] = sum_c Ob[t,c] * wo[d,c]  (fp32 out)
// ---------------------------------------------------------------------------
__global__ __launch_bounds__(256, 2) void out_gemm(
        const short* __restrict__ Ob, const short* __restrict__ wob,
        float* __restrict__ outp) {
    __shared__ short As[128 * 64];
    __shared__ short Bs[128 * 64];
    const int rowbase = blockIdx.x * 128;
    const int colbase = blockIdx.y * 128;
    const int tid = threadIdx.x;
    const int lane = tid & 63;
    const int wid = tid >> 6;
    const int wm = wid >> 1, wn = wid & 1;
    const int g = lane >> 4, c = lane & 15;

    const f32x4 z4 = {0.f, 0.f, 0.f, 0.f};
    f32x4 acc[4][4];
#pragma unroll
    for (int i = 0; i < 4; ++i)
#pragma unroll
        for (int j = 0; j < 4; ++j) acc[i][j] = z4;

    for (int kt = 0; kt < 12; ++kt) {
        __syncthreads();
#pragma unroll
        for (int p = 0; p < 4; ++p) {
            int lin = p * 256 + tid;
            int row = lin >> 3, kb = lin & 7;
            int sw = ((kb * 16) ^ ((row & 7) << 4)) >> 1;
            *(bf16x8*)&As[row * 64 + sw] = *(const bf16x8*)&Ob[(rowbase + row) * NEMB + kt * 64 + kb * 8];
            *(bf16x8*)&Bs[row * 64 + sw] = *(const bf16x8*)&wob[(colbase + row) * NEMB + kt * 64 + kb * 8];
        }
        __syncthreads();
#pragma unroll
        for (int ks = 0; ks < 2; ++ks) {
            bf16x8 a[4], b[4];
#pragma unroll
            for (int mi = 0; mi < 4; ++mi) {
                int row = wm * 64 + mi * 16 + c;
                int kb = ((ks * 64 + g * 16) ^ ((row & 7) << 4)) >> 1;
                a[mi] = *(const bf16x8*)&As[row * 64 + kb];
            }
#pragma unroll
            for (int ni = 0; ni < 4; ++ni) {
                int row = wn * 64 + ni * 16 + c;
                int kb = ((ks * 64 + g * 16) ^ ((row & 7) << 4)) >> 1;
                b[ni] = *(const bf16x8*)&Bs[row * 64 + kb];
            }
#pragma unroll
            for (int mi = 0; mi < 4; ++mi)
#pragma unroll
                for (int ni = 0; ni < 4; ++ni)
                    acc[mi][ni] = MFMA(a[mi], b[ni], acc[mi][ni]);
        }
    }
#pragma unroll
    for (int mi = 0; mi < 4; ++mi) {
        int trow0 = rowbase + wm * 64 + mi * 16 + g * 4;
#pragma unroll
        for (int ni = 0; ni < 4; ++ni) {
            int col = colbase + wn * 64 + ni * 16 + c;
#pragma unroll
            for (int r = 0; r < 4; ++r)
                outp[(size_t)(trow0 + r) * NEMB + col] = acc[mi][ni][r];
        }
    }
}

// ---------------------------------------------------------------------------
extern "C" void kernel_launch(void* const* d_in, const int* in_sizes, int n_in,
                              void* d_out, int out_size, void* d_ws, size_t ws_size,
                              hipStream_t stream) {
    (void)in_sizes; (void)n_in; (void)out_size; (void)ws_size;
    const float* x  = (const float*)d_in[0];
    const float* wq = (const float*)d_in[1];
    const float* wk = (const float*)d_in[2];
    const float* wv = (const float*)d_in[3];
    const float* wo = (const float*)d_in[4];
    float* outp = (float*)d_out;                     // final [4096][768]
    float* wout = outp + (size_t)NB * T_SEQ * NEMB;  // weights [24][2048][2048]

    char* ws = (char*)d_ws;
    size_t off = 0;
    short* xb  = (short*)(ws + off); off += (size_t)NB * T_SEQ * NEMB * 2;
    short* wqb = (short*)(ws + off); off += (size_t)NEMB * NEMB * 2;
    short* wkb = (short*)(ws + off); off += (size_t)NEMB * NEMB * 2;
    short* wvb = (short*)(ws + off); off += (size_t)NEMB * NEMB * 2;
    short* wob = (short*)(ws + off); off += (size_t)NEMB * NEMB * 2;
    short* Qh  = (short*)(ws + off); off += (size_t)NB * NH * T_SEQ * DH * 2;
    short* Kh  = (short*)(ws + off); off += (size_t)NB * NH * T_SEQ * DH * 2;
    short* Vt  = (short*)(ws + off); off += (size_t)NB * NH * T_SEQ * DH * 2;
    short* Ob  = (short*)(ws + off); off += (size_t)NB * T_SEQ * NEMB * 2;

    cvt_kernel<<<dim3(512, 5), 256, 0, stream>>>(x, wq, wk, wv, wo, xb, wqb, wkb, wvb, wob);
    qkv_gemm<<<dim3(32, 6, 3), 256, 0, stream>>>(xb, wqb, wkb, wvb, Qh, Kh, Vt);
    attn_kernel<<<dim3(16, NB * NH), 256, 0, stream>>>(Qh, Kh, Vt, wout, Ob);
    out_gemm<<<dim3(32, 6), 256, 0, stream>>>(Ob, wob, outp);
}

// Round 4
// 554.596 us; speedup vs baseline: 1.0374x; 1.0374x over previous
//
#include <hip/hip_runtime.h>
#include <stdint.h>
#include <stddef.h>

#define T_SEQ 2048
#define NH    12
#define DH    64
#define NB    2
#define NEMB  768

using f32x4  = __attribute__((ext_vector_type(4))) float;
using bf16x8 = __attribute__((ext_vector_type(8))) short;
using bf16x4 = __attribute__((ext_vector_type(4))) short;

#define MFMA(a, b, c) __builtin_amdgcn_mfma_f32_16x16x32_bf16((a), (b), (c), 0, 0, 0)

extern "C" __device__ float __ocml_native_exp2_f32(float);

__device__ __forceinline__ short f2bf(float f) {
    union { float f; uint32_t u; } v; v.f = f;
    uint32_t u = v.u + 0x7FFFu + ((v.u >> 16) & 1u);
    return (short)(u >> 16);
}
__device__ __forceinline__ float b2f(short s) {
    union { uint32_t u; float f; } v; v.u = ((uint32_t)(uint16_t)s) << 16;
    return v.f;
}

// ---------------------------------------------------------------------------
// Kernel 1: fp32 -> bf16 conversion. w_q additionally scaled by 1/8*log2(e)
// so that softmax exp becomes a single exp2.
// ---------------------------------------------------------------------------
__global__ void cvt_kernel(const float* __restrict__ x,  const float* __restrict__ wq,
                           const float* __restrict__ wk, const float* __restrict__ wv,
                           const float* __restrict__ wo,
                           short* __restrict__ xb,  short* __restrict__ wqb,
                           short* __restrict__ wkb, short* __restrict__ wvb,
                           short* __restrict__ wob) {
    const float* src; short* dst; int n; float scale = 1.0f;
    switch (blockIdx.y) {
        case 0:  src = x;  dst = xb;  n = NB * T_SEQ * NEMB; break;
        case 1:  src = wq; dst = wqb; n = NEMB * NEMB; scale = 0.18033688737f; break; // 0.125*log2(e)
        case 2:  src = wk; dst = wkb; n = NEMB * NEMB; break;
        case 3:  src = wv; dst = wvb; n = NEMB * NEMB; break;
        default: src = wo; dst = wob; n = NEMB * NEMB; break;
    }
    int n4 = n >> 2;
    for (int i = blockIdx.x * blockDim.x + threadIdx.x; i < n4; i += gridDim.x * blockDim.x) {
        float4 v = ((const float4*)src)[i];
        short4 o;
        o.x = f2bf(v.x * scale); o.y = f2bf(v.y * scale);
        o.z = f2bf(v.z * scale); o.w = f2bf(v.w * scale);
        ((short4*)dst)[i] = o;
    }
}

// ---------------------------------------------------------------------------
// Kernel 2: QKV projection GEMM.  C[t,d] = sum_c xb[t,c] * W[d,c]
// ---------------------------------------------------------------------------
__global__ __launch_bounds__(256, 2) void qkv_gemm(
        const short* __restrict__ xb,  const short* __restrict__ wqb,
        const short* __restrict__ wkb, const short* __restrict__ wvb,
        short* __restrict__ Qh, short* __restrict__ Kh, short* __restrict__ Vt) {
    __shared__ short As[128 * 64];
    __shared__ short Bs[128 * 64];
    const int mode = blockIdx.z;
    const short* Wm = (mode == 0) ? wqb : (mode == 1) ? wkb : wvb;
    const int rowbase = blockIdx.x * 128;
    const int colbase = blockIdx.y * 128;
    const int tid = threadIdx.x;
    const int lane = tid & 63;
    const int wid = tid >> 6;
    const int wm = wid >> 1, wn = wid & 1;
    const int g = lane >> 4, c = lane & 15;

    const f32x4 z4 = {0.f, 0.f, 0.f, 0.f};
    f32x4 acc[4][4];
#pragma unroll
    for (int i = 0; i < 4; ++i)
#pragma unroll
        for (int j = 0; j < 4; ++j) acc[i][j] = z4;

    for (int kt = 0; kt < 12; ++kt) {
        __syncthreads();
#pragma unroll
        for (int p = 0; p < 4; ++p) {
            int lin = p * 256 + tid;
            int row = lin >> 3, kb = lin & 7;
            int sw = ((kb * 16) ^ ((row & 7) << 4)) >> 1;
            *(bf16x8*)&As[row * 64 + sw] = *(const bf16x8*)&xb[(rowbase + row) * NEMB + kt * 64 + kb * 8];
            *(bf16x8*)&Bs[row * 64 + sw] = *(const bf16x8*)&Wm[(colbase + row) * NEMB + kt * 64 + kb * 8];
        }
        __syncthreads();
#pragma unroll
        for (int ks = 0; ks < 2; ++ks) {
            bf16x8 a[4], b[4];
#pragma unroll
            for (int mi = 0; mi < 4; ++mi) {
                int row = wm * 64 + mi * 16 + c;
                int kb = ((ks * 64 + g * 16) ^ ((row & 7) << 4)) >> 1;
                a[mi] = *(const bf16x8*)&As[row * 64 + kb];
            }
#pragma unroll
            for (int ni = 0; ni < 4; ++ni) {
                int row = wn * 64 + ni * 16 + c;
                int kb = ((ks * 64 + g * 16) ^ ((row & 7) << 4)) >> 1;
                b[ni] = *(const bf16x8*)&Bs[row * 64 + kb];
            }
#pragma unroll
            for (int mi = 0; mi < 4; ++mi)
#pragma unroll
                for (int ni = 0; ni < 4; ++ni)
                    acc[mi][ni] = MFMA(a[mi], b[ni], acc[mi][ni]);
        }
    }
#pragma unroll
    for (int mi = 0; mi < 4; ++mi) {
        int trow0 = rowbase + wm * 64 + mi * 16 + g * 4;
#pragma unroll
        for (int ni = 0; ni < 4; ++ni) {
            int col = colbase + wn * 64 + ni * 16 + c;
            int h = col >> 6, dh = col & 63;
#pragma unroll
            for (int r = 0; r < 4; ++r) {
                int trow = trow0 + r;
                int bb = trow >> 11, t = trow & 2047;
                int bh = bb * NH + h;
                short val = f2bf(acc[mi][ni][r]);
                if (mode == 2)      Vt[(size_t)bh * (DH * T_SEQ) + dh * T_SEQ + t] = val;
                else if (mode == 0) Qh[((size_t)bh * T_SEQ + t) * DH + dh] = val;
                else                Kh[((size_t)bh * T_SEQ + t) * DH + dh] = val;
            }
        }
    }
}

// ---------------------------------------------------------------------------
// Kernel 3: fused causal attention, swapped-QK layout.
// Snake-paired 1-D grid: block i<256 -> (bh=i>>4, qt=i&15);
// i>=256 -> (bh=16+(k>>4), qt=15-(k&15)).  Round-robin dispatch puts blocks
// i and i+256 on the same CU-slot; their qtiles sum to 15 -> per-CU work is
// a constant 34 k-tile units instead of worst-case 64 (same-qtile pairing).
// ---------------------------------------------------------------------------
__global__ __launch_bounds__(256, 2) void attn_kernel(
        const short* __restrict__ Qh, const short* __restrict__ Kh,
        const short* __restrict__ Vt, float* __restrict__ Wout,
        short* __restrict__ Ob) {
    __shared__ short Ks[64 * 64];
    __shared__ short Vs[64 * 64];
    __shared__ short Ps[4][32 * 64];

    int bh, qtile;
    {
        int i = blockIdx.x;
        if (i < 256) { bh = i >> 4; qtile = i & 15; }
        else { int k = i - 256; bh = 16 + (k >> 4); qtile = 15 - (k & 15); }
    }
    const int bb = bh / NH, h = bh % NH;
    const int qbase = qtile * 128;
    const int tid = threadIdx.x, lane = tid & 63, w = tid >> 6;
    const int g = lane >> 4, c = lane & 15;
    const int nkt = 2 * (qtile + 1);
    const int stripmax = qbase + w * 32 + 31;

    const short* Qp = Qh + (size_t)bh * T_SEQ * DH;
    const short* Kp = Kh + (size_t)bh * T_SEQ * DH;
    const short* Vp = Vt + (size_t)bh * DH * T_SEQ;
    float* Wp = Wout + (size_t)bh * T_SEQ * T_SEQ;

    const f32x4 z4 = {0.f, 0.f, 0.f, 0.f};

    // Q fragments (B-operand now): row = c, k = g*8+i
    bf16x8 q[2][2];
#pragma unroll
    for (int mi = 0; mi < 2; ++mi)
#pragma unroll
        for (int ks = 0; ks < 2; ++ks)
            q[mi][ks] = *(const bf16x8*)&Qp[(qbase + w * 32 + mi * 16 + c) * DH + ks * 32 + g * 8];

    // ---- pass 1: denominators ----
    float lsum[2] = {0.f, 0.f};
    for (int kt = 0; kt < nkt; ++kt) {
        __syncthreads();
#pragma unroll
        for (int p = 0; p < 2; ++p) {
            int lin = p * 256 + tid;
            int row = lin >> 3, kb = lin & 7;
            int sw = ((kb * 16) ^ ((row & 7) << 4)) >> 1;
            *(bf16x8*)&Ks[row * 64 + sw] = *(const bf16x8*)&Kp[(kt * 64 + row) * DH + kb * 8];
        }
        __syncthreads();
        if (kt * 64 > stripmax) continue;
#pragma unroll
        for (int ni = 0; ni < 4; ++ni) {
            f32x4 s[2] = {z4, z4};
#pragma unroll
            for (int ks = 0; ks < 2; ++ks) {
                int krow = ni * 16 + c;
                int kb = ((ks * 64 + g * 16) ^ ((krow & 7) << 4)) >> 1;
                bf16x8 kf = *(const bf16x8*)&Ks[krow * 64 + kb];
                s[0] = MFMA(kf, q[0][ks], s[0]);   // swapped: D col = q-row, D row = k-col
                s[1] = MFMA(kf, q[1][ks], s[1]);
            }
            int bcol = kt * 64 + ni * 16 + g * 4;
#pragma unroll
            for (int mi = 0; mi < 2; ++mi) {
                int rowg = qbase + w * 32 + mi * 16 + c;
#pragma unroll
                for (int r = 0; r < 4; ++r) {
                    float e = __ocml_native_exp2_f32(s[mi][r]);
                    lsum[mi] += (bcol + r <= rowg) ? e : 0.f;
                }
            }
        }
    }
    float rl[2];
#pragma unroll
    for (int mi = 0; mi < 2; ++mi) {
        float t = lsum[mi];
        t += __shfl_xor(t, 16);
        t += __shfl_xor(t, 32);
        rl[mi] = __builtin_amdgcn_rcpf(t);
    }

    // ---- pass 2: P -> LDS, W full-line writes, PV ----
    f32x4 o[2][4];
#pragma unroll
    for (int mi = 0; mi < 2; ++mi)
#pragma unroll
        for (int di = 0; di < 4; ++di) o[mi][di] = z4;

    const int wl8 = lane >> 3;          // 0..7: row-within-8 for the W writer
    const int cl8 = lane & 7;           // 0..7: 8-col group for the W writer

    for (int kt = 0; kt < nkt; ++kt) {
        __syncthreads();
#pragma unroll
        for (int p = 0; p < 2; ++p) {
            int lin = p * 256 + tid;
            int row = lin >> 3, kb = lin & 7;
            int sw = ((kb * 16) ^ ((row & 7) << 4)) >> 1;
            *(bf16x8*)&Ks[row * 64 + sw] = *(const bf16x8*)&Kp[(kt * 64 + row) * DH + kb * 8];
            *(bf16x8*)&Vs[row * 64 + sw] = *(const bf16x8*)&Vp[row * T_SEQ + kt * 64 + kb * 8];
        }
        __syncthreads();
        if (kt * 64 > stripmax) {
            // fully masked: contiguous 256B-per-row zero stores
#pragma unroll
            for (int it = 0; it < 4; ++it) {
                float* dst = Wp + (size_t)(qbase + w * 32 + it * 8 + wl8) * T_SEQ + kt * 64 + cl8 * 8;
                __builtin_nontemporal_store(z4, (f32x4*)dst);
                __builtin_nontemporal_store(z4, (f32x4*)(dst + 4));
            }
            continue;
        }
        // QK^T (swapped) + normalize + pack P into LDS
#pragma unroll
        for (int ni = 0; ni < 4; ++ni) {
            f32x4 s[2] = {z4, z4};
#pragma unroll
            for (int ks = 0; ks < 2; ++ks) {
                int krow = ni * 16 + c;
                int kb = ((ks * 64 + g * 16) ^ ((krow & 7) << 4)) >> 1;
                bf16x8 kf = *(const bf16x8*)&Ks[krow * 64 + kb];
                s[0] = MFMA(kf, q[0][ks], s[0]);
                s[1] = MFMA(kf, q[1][ks], s[1]);
            }
            int bcol = kt * 64 + ni * 16 + g * 4;
#pragma unroll
            for (int mi = 0; mi < 2; ++mi) {
                int rowg = qbase + w * 32 + mi * 16 + c;
                bf16x4 pk;
#pragma unroll
                for (int r = 0; r < 4; ++r) {
                    float e = __ocml_native_exp2_f32(s[mi][r]) * rl[mi];
                    float wgt = (bcol + r <= rowg) ? e : 0.f;
                    pk[r] = f2bf(wgt);
                }
                int prow = mi * 16 + c;
                int sw = ((ni * 32 + g * 8) ^ ((prow & 7) << 4)) >> 1;
                *(bf16x4*)&Ps[w][prow * 64 + sw] = pk;
            }
        }
        // PV: O += P @ V   (A = P from LDS, B = V^T from LDS)
#pragma unroll
        for (int ks = 0; ks < 2; ++ks) {
            bf16x8 pa[2];
#pragma unroll
            for (int mi = 0; mi < 2; ++mi) {
                int prow = mi * 16 + c;
                int kb = ((ks * 64 + g * 16) ^ ((prow & 7) << 4)) >> 1;
                pa[mi] = *(const bf16x8*)&Ps[w][prow * 64 + kb];
            }
#pragma unroll
            for (int di = 0; di < 4; ++di) {
                int vrow = di * 16 + c;
                int kb = ((ks * 64 + g * 16) ^ ((vrow & 7) << 4)) >> 1;
                bf16x8 vf = *(const bf16x8*)&Vs[vrow * 64 + kb];
                o[0][di] = MFMA(pa[0], vf, o[0][di]);
                o[1][di] = MFMA(pa[1], vf, o[1][di]);
            }
        }
        // W writer: re-read own P strip, store contiguous 256B per row (fp32)
#pragma unroll
        for (int it = 0; it < 4; ++it) {
            int prow = it * 8 + wl8;
            int sw = ((cl8 * 16) ^ ((prow & 7) << 4)) >> 1;
            bf16x8 pv8 = *(const bf16x8*)&Ps[w][prow * 64 + sw];
            float* dst = Wp + (size_t)(qbase + w * 32 + prow) * T_SEQ + kt * 64 + cl8 * 8;
            f32x4 lo = {b2f(pv8[0]), b2f(pv8[1]), b2f(pv8[2]), b2f(pv8[3])};
            f32x4 hi = {b2f(pv8[4]), b2f(pv8[5]), b2f(pv8[6]), b2f(pv8[7])};
            __builtin_nontemporal_store(lo, (f32x4*)dst);
            __builtin_nontemporal_store(hi, (f32x4*)(dst + 4));
        }
    }

    // zero-fill strictly-upper region beyond the block's tiles
    int c0 = nkt * 64;
    if (c0 < T_SEQ) {
        for (int r = 0; r < 128; ++r) {
            float* base = Wp + (size_t)(qbase + r) * T_SEQ;
            for (int cc = c0 + tid * 4; cc < T_SEQ; cc += 1024)
                __builtin_nontemporal_store(z4, (f32x4*)(base + cc));
        }
    }

    // write O (bf16) into [4096][768] for the output projection
#pragma unroll
    for (int mi = 0; mi < 2; ++mi)
#pragma unroll
        for (int di = 0; di < 4; ++di)
#pragma unroll
            for (int r = 0; r < 4; ++r) {
                int rowg = qbase + w * 32 + mi * 16 + g * 4 + r;
                Ob[(size_t)(bb * T_SEQ + rowg) * NEMB + h * 64 + di * 16 + c] = f2bf(o[mi][di][r]);
            }
}

// ---------------------------------------------------------------------------
// Kernel 4: output projection.  final[t,d] = sum_c Ob[t,c] * wo[d,c]  (fp32 out)
// ---------------------------------------------------------------------------
__global__ __launch_bounds__(256, 2) void out_gemm(
        const short* __restrict__ Ob, const short* __restrict__ wob,
        float* __restrict__ outp) {
    __shared__ short As[128 * 64];
    __shared__ short Bs[128 * 64];
    const int rowbase = blockIdx.x * 128;
    const int colbase = blockIdx.y * 128;
    const int tid = threadIdx.x;
    const int lane = tid & 63;
    const int wid = tid >> 6;
    const int wm = wid >> 1, wn = wid & 1;
    const int g = lane >> 4, c = lane & 15;

    const f32x4 z4 = {0.f, 0.f, 0.f, 0.f};
    f32x4 acc[4][4];
#pragma unroll
    for (int i = 0; i < 4; ++i)
#pragma unroll
        for (int j = 0; j < 4; ++j) acc[i][j] = z4;

    for (int kt = 0; kt < 12; ++kt) {
        __syncthreads();
#pragma unroll
        for (int p = 0; p < 4; ++p) {
            int lin = p * 256 + tid;
            int row = lin >> 3, kb = lin & 7;
            int sw = ((kb * 16) ^ ((row & 7) << 4)) >> 1;
            *(bf16x8*)&As[row * 64 + sw] = *(const bf16x8*)&Ob[(rowbase + row) * NEMB + kt * 64 + kb * 8];
            *(bf16x8*)&Bs[row * 64 + sw] = *(const bf16x8*)&wob[(colbase + row) * NEMB + kt * 64 + kb * 8];
        }
        __syncthreads();
#pragma unroll
        for (int ks = 0; ks < 2; ++ks) {
            bf16x8 a[4], b[4];
#pragma unroll
            for (int mi = 0; mi < 4; ++mi) {
                int row = wm * 64 + mi * 16 + c;
                int kb = ((ks * 64 + g * 16) ^ ((row & 7) << 4)) >> 1;
                a[mi] = *(const bf16x8*)&As[row * 64 + kb];
            }
#pragma unroll
            for (int ni = 0; ni < 4; ++ni) {
                int row = wn * 64 + ni * 16 + c;
                int kb = ((ks * 64 + g * 16) ^ ((row & 7) << 4)) >> 1;
                b[ni] = *(const bf16x8*)&Bs[row * 64 + kb];
            }
#pragma unroll
            for (int mi = 0; mi < 4; ++mi)
#pragma unroll
                for (int ni = 0; ni < 4; ++ni)
                    acc[mi][ni] = MFMA(a[mi], b[ni], acc[mi][ni]);
        }
    }
#pragma unroll
    for (int mi = 0; mi < 4; ++mi) {
        int trow0 = rowbase + wm * 64 + mi * 16 + g * 4;
#pragma unroll
        for (int ni = 0; ni < 4; ++ni) {
            int col = colbase + wn * 64 + ni * 16 + c;
#pragma unroll
            for (int r = 0; r < 4; ++r)
                outp[(size_t)(trow0 + r) * NEMB + col] = acc[mi][ni][r];
        }
    }
}

// ---------------------------------------------------------------------------
extern "C" void kernel_launch(void* const* d_in, const int* in_sizes, int n_in,
                              void* d_out, int out_size, void* d_ws, size_t ws_size,
                              hipStream_t stream) {
    (void)in_sizes; (void)n_in; (void)out_size; (void)ws_size;
    const float* x  = (const float*)d_in[0];
    const float* wq = (const float*)d_in[1];
    const float* wk = (const float*)d_in[2];
    const float* wv = (const float*)d_in[3];
    const float* wo = (const float*)d_in[4];
    float* outp = (float*)d_out;                     // final [4096][768]
    float* wout = outp + (size_t)NB * T_SEQ * NEMB;  // weights [24][2048][2048]

    char* ws = (char*)d_ws;
    size_t off = 0;
    short* xb  = (short*)(ws + off); off += (size_t)NB * T_SEQ * NEMB * 2;
    short* wqb = (short*)(ws + off); off += (size_t)NEMB * NEMB * 2;
    short* wkb = (short*)(ws + off); off += (size_t)NEMB * NEMB * 2;
    short* wvb = (short*)(ws + off); off += (size_t)NEMB * NEMB * 2;
    short* wob = (short*)(ws + off); off += (size_t)NEMB * NEMB * 2;
    short* Qh  = (short*)(ws + off); off += (size_t)NB * NH * T_SEQ * DH * 2;
    short* Kh  = (short*)(ws + off); off += (size_t)NB * NH * T_SEQ * DH * 2;
    short* Vt  = (short*)(ws + off); off += (size_t)NB * NH * T_SEQ * DH * 2;
    short* Ob  = (short*)(ws + off); off += (size_t)NB * T_SEQ * NEMB * 2;

    cvt_kernel<<<dim3(512, 5), 256, 0, stream>>>(x, wq, wk, wv, wo, xb, wqb, wkb, wvb, wob);
    qkv_gemm<<<dim3(32, 6, 3), 256, 0, stream>>>(xb, wqb, wkb, wvb, Qh, Kh, Vt);
    attn_kernel<<<dim3(384), 256, 0, stream>>>(Qh, Kh, Vt, wout, Ob);
    out_gemm<<<dim3(32, 6), 256, 0, stream>>>(Ob, wob, outp);
}